// Round 2
// baseline (416.261 us; speedup 1.0000x reference)
//
#include <hip/hip_runtime.h>
#include <math.h>

// FCNNSlopeValuationFunction: per-row angle -> zone -> gather dir[row, zone],
// masked by z_1[:,0] != 0.
//
// Numerics (bit-exact vs numpy-f32 reference):
//  - Zone is a pure function of t = int(phi_ref); downstream integer math is
//    exact (((pcs+11)/22 f32-floor == integer divide for pcs in [0,359]).
//  - Fast path: ocml atan2f (<=6 ulp => <~1e-4 deg error). Probe zone at
//    floor(phi +/- 2^-7 deg); if both probes agree, the zone is provably the
//    reference's. Wrap at 0/360 handled in mod-360 t-space.
//  - Slow path (~0.07% of lanes): correctly-rounded f32 atan2 via double +
//    f32 degrees multiply (no fma contraction) — the verified-exact path.
//
// Memory structure (this round's change): one thread processes ITER=4 rows,
// block-strided so every load instruction stays wave-coalesced. All 12
// vector loads (4x z1-float4, 4x ry, 8x dir-float4) are issued before any
// compute -> 4x memory-level parallelism per thread, 4x fewer blocks.
// Round-1 lesson: kernel is memory/latency-bound (removing 99.9% of f64
// atan2 work changed nothing), so attack the memory pipeline, not VALU.

constexpr int ITER = 4;
constexpr int TPB  = 256;

__device__ __forceinline__ int zone_of(int t) {
    // t in [0, 360]; pcs = (90 + t) % 360; zone = ((pcs + 11) / 22) % 8
    int pcs = 90 + t;
    if (pcs >= 360) pcs -= 360;
    return ((pcs + 11) / 22) & 7;
}

__device__ __forceinline__ float row_val(float4 a, float ry, float4 d0, float4 d1) {
#pragma clang fp contract(off)
    float dx = a.w - a.y;                     // rx - lx   (f32, matches ref)
    float dy = -(ry - a.z);                   // -(ry - ly) incl. signed-zero

    // fast path: f32 atan2, zone probed at +/- EPS
    float pf = atan2f(dy, dx) * 57.29577951308232f;
    if (pf < 0.0f) pf = 360.0f + pf;          // pf in [0, 360]

    const float EPS = 0.0078125f;             // 2^-7 deg; fast-path err <~1e-4
    int t_lo = (int)floorf(pf - EPS);         // may be -1 near 0
    int t_hi = (int)floorf(pf + EPS);         // may be 360 near 360
    if (t_lo < 0) t_lo += 360;                // zone continuous across wrap
    int zone = zone_of(t_lo);
    if (zone != zone_of(t_hi)) {
        // slow path (rare): exact, matches reference bit-for-bit
        float phi_rad = (float)atan2((double)dy, (double)dx);
        float phi = phi_rad * 57.29577951308232f;
        if (phi < 0.0f) phi = 360.0f + phi;   // f32 add, matches ref
        zone = zone_of((int)phi);             // trunc == floor (phi >= 0)
    }

    // select dir[zone] from registers: 7 cndmasks
    float e0 = (zone & 1) ? d0.y : d0.x;
    float e1 = (zone & 1) ? d0.w : d0.z;
    float e2 = (zone & 1) ? d1.y : d1.x;
    float e3 = (zone & 1) ? d1.w : d1.z;
    float f0 = (zone & 2) ? e1 : e0;
    float f1 = (zone & 2) ? e3 : e2;
    float g  = (zone & 4) ? f1 : f0;

    return (a.x != 0.0f) ? g : 0.0f;
}

__global__ __launch_bounds__(TPB) void slope_zone_kernel(
    const float* __restrict__ z1,
    const float* __restrict__ dir,
    float* __restrict__ out,
    int n)
{
    int base = blockIdx.x * (TPB * ITER) + threadIdx.x;

    float4 a[ITER]; float ry[ITER]; float4 d0[ITER], d1[ITER];

    if (base + (ITER - 1) * TPB < n) {
        // full block: no per-row guards, all loads issued up front
#pragma unroll
        for (int k = 0; k < ITER; ++k) {
            size_t i = (size_t)(base + k * TPB);
            a[k]  = *reinterpret_cast<const float4*>(z1 + i * 16);
            ry[k] = z1[i * 16 + 4];
            const float4* dr = reinterpret_cast<const float4*>(dir + i * 8);
            d0[k] = dr[0];
            d1[k] = dr[1];
        }
#pragma unroll
        for (int k = 0; k < ITER; ++k)
            out[base + k * TPB] = row_val(a[k], ry[k], d0[k], d1[k]);
    } else {
        // tail block: per-row guard
#pragma unroll
        for (int k = 0; k < ITER; ++k) {
            int i = base + k * TPB;
            if (i < n) {
                float4 av  = *reinterpret_cast<const float4*>(z1 + (size_t)i * 16);
                float  ryv = z1[(size_t)i * 16 + 4];
                const float4* dr = reinterpret_cast<const float4*>(dir + (size_t)i * 8);
                out[i] = row_val(av, ryv, dr[0], dr[1]);
            }
        }
    }
}

extern "C" void kernel_launch(void* const* d_in, const int* in_sizes, int n_in,
                              void* d_out, int out_size, void* d_ws, size_t ws_size,
                              hipStream_t stream) {
    const float* z1  = (const float*)d_in[0];   // (B,16) f32
    const float* dir = (const float*)d_in[1];   // (B,8)  f32
    float* out = (float*)d_out;                 // (B,)   f32
    int n = out_size;
    int rows_per_block = TPB * ITER;
    int blocks = (n + rows_per_block - 1) / rows_per_block;
    hipLaunchKernelGGL(slope_zone_kernel, dim3(blocks), dim3(TPB), 0, stream,
                       z1, dir, out, n);
}